// Round 13
// baseline (32.059 us; speedup 1.0000x reference)
//
#include <hip/hip_runtime.h>

#define CPN  1000
#define NAUX (CPN + 3)   // 1003 aux points / knots (idx 0..1002)
#define M    4096        // uniform resample intervals
#define EPSF 1e-7f

// unpack low/high f16 of u32 -> f32
static __device__ __forceinline__ float h2f_lo(unsigned int u) {
    unsigned short us = (unsigned short)u;
    __fp16 h = *reinterpret_cast<__fp16*>(&us);
    return (float)h;
}
static __device__ __forceinline__ float h2f_hi(unsigned int u) {
    unsigned short us = (unsigned short)(u >> 16);
    __fp16 h = *reinterpret_cast<__fp16*>(&us);
    return (float)h;
}
// pack two f32 -> u32 of two f16, round-to-nearest (v_cvt_f16_f32)
static __device__ __forceinline__ unsigned int pk2h_rtn(float a, float b) {
    __fp16 ha = (__fp16)a, hb = (__fp16)b;
    unsigned short ua = *reinterpret_cast<unsigned short*>(&ha);
    unsigned short ub = *reinterpret_cast<unsigned short*>(&hb);
    return (unsigned int)ua | ((unsigned int)ub << 16);
}

// ---------------------------------------------------------------------------
// Setup (1 block, 1024 thr): aux -> knots (scan) -> exact per-segment cubics
// (f32, LDS) -> uniform-grid Hermite resample: per interval, eval true
// f and f' at both endpoints (C1-continuous), fit cubic, pack 8xf16.
// ---------------------------------------------------------------------------
__global__ __launch_bounds__(1024)
void spline_setup(const float* __restrict__ cps,
                  uint4* __restrict__ g_rec,    // M x 16B f16 interval records
                  float* __restrict__ g_meta)   // {lo, hi, w, inv_w}
{
    __shared__ float sax[NAUX];
    __shared__ float say[NAUX];
    __shared__ float skn[NAUX + 1];
    __shared__ float wsum[16];
    __shared__ float segc[8 * CPN];   // 32 KB exact segment coeffs
    const int tid = threadIdx.x;

    const float c0x = cps[0],         c0y = cps[1];
    const float c1x = cps[2],         c1y = cps[3];
    const float cLx = cps[2*(CPN-1)], cLy = cps[2*(CPN-1)+1];
    const float dx01 = c0x - c1x, dy01 = c0y - c1y;
    const float dxL  = c0x - cLx, dyL  = c0y - cLy;
    const float l01   = sqrtf(dx01*dx01 + dy01*dy01 + EPSF);
    const float llast = sqrtf(dxL*dxL   + dyL*dyL   + EPSF);

    if (tid < CPN) { sax[tid+1] = cps[2*tid]; say[tid+1] = cps[2*tid+1]; }
    if (tid == 0) {
        sax[0]     = c0x - (l01/llast) * dxL;
        say[0]     = c0y - (l01/llast) * dyL;
        sax[CPN+1] = c0x;  say[CPN+1] = c0y;
        sax[CPN+2] = c0x + (llast/l01) * (c1x - c0x);
        say[CPN+2] = c0y + (llast/l01) * (c1y - c0y);
    }
    __syncthreads();

    // seg lengths ^(1/2 of sqrt) ; wave scan -> knots
    float v = 0.f;
    if (tid < NAUX - 1) {
        const float dx = sax[tid+1] - sax[tid];
        const float dy = say[tid+1] - say[tid];
        v = sqrtf(sqrtf(dx*dx + dy*dy));
    }
    #pragma unroll
    for (int off = 1; off < 64; off <<= 1) {
        const float w_ = __shfl_up(v, off, 64);
        if ((tid & 63) >= off) v += w_;
    }
    if ((tid & 63) == 63) wsum[tid >> 6] = v;
    __syncthreads();
    if (tid < 16) {
        float x = wsum[tid];
        #pragma unroll
        for (int off = 1; off < 16; off <<= 1) {
            const float w_ = __shfl_up(x, off, 16);
            if (tid >= off) x += w_;
        }
        wsum[tid] = x;
    }
    __syncthreads();
    const float incl = v + ((tid >= 64) ? wsum[(tid >> 6) - 1] : 0.f);

    if (tid == 0)       { skn[0] = 0.f; skn[NAUX] = 1e30f; }
    if (tid < NAUX - 1) { skn[tid+1] = incl; }
    __syncthreads();

    // exact per-segment cubics in u = t - skn[sg]  (verified R6-R12)
    if (tid < CPN) {
        const int sg = tid + 1;
        const float t0 = skn[sg-1], t1 = skn[sg], t2 = skn[sg+1], t3 = skn[sg+2];
        const float A = t1 - t0, B = t2 - t1, C = t3 - t2;
        const float r01 = 1.0f / A;
        const float r12 = 1.0f / B;
        const float r23 = 1.0f / C;
        const float r02 = 1.0f / (A + B);
        const float r13 = 1.0f / (B + C);
        const float C3  = B + C;

        const float P0x = sax[sg-1], P0y = say[sg-1];
        const float P1x = sax[sg],   P1y = say[sg];
        const float P2x = sax[sg+1], P2y = say[sg+1];
        const float P3x = sax[sg+2], P3y = say[sg+2];

        const float L01_1x = (P1x - P0x) * r01, L01_1y = (P1y - P0y) * r01;
        const float L12_1x = (P2x - P1x) * r12, L12_1y = (P2y - P1y) * r12;
        const float L23_0x = ((B + C) * P2x - B * P3x) * r23;
        const float L23_0y = ((B + C) * P2y - B * P3y) * r23;
        const float L23_1x = (P3x - P2x) * r23, L23_1y = (P3y - P2y) * r23;

        const float Q012_0x = (B * P1x + A * P1x) * r02;
        const float Q012_0y = (B * P1y + A * P1y) * r02;
        const float Q012_1x = (B * L01_1x - P1x + A * L12_1x + P1x) * r02;
        const float Q012_1y = (B * L01_1y - P1y + A * L12_1y + P1y) * r02;
        const float Q012_2x = (L12_1x - L01_1x) * r02;
        const float Q012_2y = (L12_1y - L01_1y) * r02;

        const float Q123_0x = C3 * P1x * r13;
        const float Q123_0y = C3 * P1y * r13;
        const float Q123_1x = (C3 * L12_1x - P1x + L23_0x) * r13;
        const float Q123_1y = (C3 * L12_1y - P1y + L23_0y) * r13;
        const float Q123_2x = (L23_1x - L12_1x) * r13;
        const float Q123_2y = (L23_1y - L12_1y) * r13;

        float* c = &segc[(size_t)tid * 8];
        c[0] = B * Q012_0x * r12;
        c[1] = (B * Q012_1x - Q012_0x + Q123_0x) * r12;
        c[2] = (B * Q012_2x - Q012_1x + Q123_1x) * r12;
        c[3] = (Q123_2x - Q012_2x) * r12;
        c[4] = B * Q012_0y * r12;
        c[5] = (B * Q012_1y - Q012_0y + Q123_0y) * r12;
        c[6] = (B * Q012_2y - Q012_1y + Q123_1y) * r12;
        c[7] = (Q123_2y - Q012_2y) * r12;
    }
    __syncthreads();

    const float lo = skn[1];
    const float hi = skn[CPN + 1];
    const float w  = (hi - lo) / (float)M;
    const float iw = (float)M / (hi - lo);

    if (tid == 0) {
        g_meta[0] = lo; g_meta[1] = hi; g_meta[2] = w; g_meta[3] = iw;
    }

    // Hermite resample: per interval i, true (f, f') at both endpoints
    for (int i = tid; i < M; i += 1024) {
        float f[2][2], d[2][2];   // [endpoint][axis]
        #pragma unroll
        for (int ep = 0; ep < 2; ++ep) {
            const float x = lo + (float)(i + ep) * w;
            int l = 0, h = 1003;
            #pragma unroll
            for (int it = 0; it < 10; ++it) {
                const int mid = (l + h) >> 1;
                const bool cnd = (skn[mid] <= x);
                l = cnd ? mid : l;
                h = cnd ? h : mid;
            }
            int s = l < 1 ? 1 : (l > CPN ? CPN : l);
            const float u = x - skn[s];
            const float* c = &segc[(size_t)(s - 1) * 8];
            f[ep][0] = fmaf(fmaf(fmaf(c[3], u, c[2]), u, c[1]), u, c[0]);
            d[ep][0] = fmaf(fmaf(3.0f * c[3], u, 2.0f * c[2]), u, c[1]);
            f[ep][1] = fmaf(fmaf(fmaf(c[7], u, c[6]), u, c[5]), u, c[4]);
            d[ep][1] = fmaf(fmaf(3.0f * c[7], u, 2.0f * c[6]), u, c[5]);
        }
        // Hermite -> power basis on [0,w]
        float cc[4][2];
        #pragma unroll
        for (int ax = 0; ax < 2; ++ax) {
            const float f0 = f[0][ax], f1 = f[1][ax];
            const float d0 = d[0][ax], d1 = d[1][ax];
            const float iwv = 1.0f / w;
            const float D = (f1 - f0) * iwv;
            cc[0][ax] = f0;
            cc[1][ax] = d0;
            cc[2][ax] = (3.0f * D - 2.0f * d0 - d1) * iwv;
            cc[3][ax] = (d0 + d1 - 2.0f * D) * iwv * iwv;
        }
        uint4 r;
        r.x = pk2h_rtn(cc[0][0], cc[0][1]);
        r.y = pk2h_rtn(cc[1][0], cc[1][1]);
        r.z = pk2h_rtn(cc[2][0], cc[2][1]);
        r.w = pk2h_rtn(cc[3][0], cc[3][1]);
        g_rec[i] = r;
    }
}

// ---------------------------------------------------------------------------
// Eval: 512 blocks x 1024 thr, 64KB LDS -> 2 blocks/CU (32 waves, 100%).
// Per query: ONE b128 LDS gather + 2 Horners. No LUT, no select, no walk.
// Pair-granular fully-coalesced I/O (R10); groups of 4 batched (R12).
// ---------------------------------------------------------------------------
__global__ __launch_bounds__(1024, 8)
void spline_eval(const float* __restrict__ tq,
                 const uint4* __restrict__ g_rec,
                 const float* __restrict__ g_meta,
                 float* __restrict__ out,   // n*2 floats
                 int n)
{
    __shared__ __align__(16) uint4 s_rec[M];   // 64 KB exactly
    const int tid = threadIdx.x;

    for (int i = tid; i < M; i += 1024) s_rec[i] = g_rec[i];

    // uniform scalar loads (pointer uniform -> s_load)
    const float lo    = g_meta[0];
    const float w     = g_meta[2];
    const float inv_w = g_meta[3];
    __syncthreads();

    const int gid = blockIdx.x * 1024 + tid;
    const int T   = gridDim.x * 1024;    // total threads (524288)
    const int P   = n >> 1;              // query pairs (4194304)

    const float2* tq2  = (const float2*)tq;
    float4*       out4 = (float4*)out;

    for (int p0 = gid; p0 < P; p0 += 4 * T) {
        const int p1 = p0 + T, p2 = p0 + 2 * T, p3 = p0 + 3 * T;
        const bool b1 = p1 < P, b2 = p2 < P, b3 = p3 < P;

        const float2 ta = tq2[p0];
        const float2 tb = b1 ? tq2[p1] : ta;
        const float2 tc = b2 ? tq2[p2] : ta;
        const float2 td = b3 ? tq2[p3] : ta;

        #pragma unroll
        for (int g = 0; g < 2; ++g) {
            float tv[4];
            if (g == 0) { tv[0] = ta.x; tv[1] = ta.y; tv[2] = tb.x; tv[3] = tb.y; }
            else        { tv[0] = tc.x; tv[1] = tc.y; tv[2] = td.x; tv[3] = td.y; }

            // phase 1: buckets + 4 independent b128 gathers
            int bb[4];
            #pragma unroll
            for (int q = 0; q < 4; ++q) {
                int b = (int)((tv[q] - lo) * inv_w);
                bb[q] = b < 0 ? 0 : (b > M - 1 ? M - 1 : b);
            }
            uint4 r[4];
            #pragma unroll
            for (int q = 0; q < 4; ++q) r[q] = s_rec[bb[q]];

            // phase 2: local coordinate + Horner
            float rx[4], ry[4];
            #pragma unroll
            for (int q = 0; q < 4; ++q) {
                const float u = tv[q] - fmaf((float)bb[q], w, lo);
                rx[q] = fmaf(fmaf(fmaf(h2f_lo(r[q].w), u, h2f_lo(r[q].z)), u, h2f_lo(r[q].y)), u, h2f_lo(r[q].x));
                ry[q] = fmaf(fmaf(fmaf(h2f_hi(r[q].w), u, h2f_hi(r[q].z)), u, h2f_hi(r[q].y)), u, h2f_hi(r[q].x));
            }

            if (g == 0) {
                out4[p0] = make_float4(rx[0], ry[0], rx[1], ry[1]);
                if (b1) out4[p1] = make_float4(rx[2], ry[2], rx[3], ry[3]);
            } else {
                if (b2) out4[p2] = make_float4(rx[0], ry[0], rx[1], ry[1]);
                if (b3) out4[p3] = make_float4(rx[2], ry[2], rx[3], ry[3]);
            }
        }
    }

    // tail (n odd) — not hit for N=8388608
    if ((n & 1) && gid == 0) {
        const int q = n - 1;
        const float t = tq[q];
        int b = (int)((t - lo) * inv_w);
        b = b < 0 ? 0 : (b > M - 1 ? M - 1 : b);
        const float u = t - fmaf((float)b, w, lo);
        const uint4 r = s_rec[b];
        out[2*q]     = fmaf(fmaf(fmaf(h2f_lo(r.w), u, h2f_lo(r.z)), u, h2f_lo(r.y)), u, h2f_lo(r.x));
        out[2*q + 1] = fmaf(fmaf(fmaf(h2f_hi(r.w), u, h2f_hi(r.z)), u, h2f_hi(r.y)), u, h2f_hi(r.x));
    }
}

extern "C" void kernel_launch(void* const* d_in, const int* in_sizes, int n_in,
                              void* d_out, int out_size, void* d_ws, size_t ws_size,
                              hipStream_t stream) {
    const float* cps = (const float*)d_in[0];
    const float* tq  = (const float*)d_in[1];
    float* out       = (float*)d_out;
    const int n      = in_sizes[1];

    // ws layout (bytes): [0, 65536) rec 16B x 4096 | [65536, 65552) meta
    uint4* g_rec  = (uint4*)d_ws;
    float* g_meta = (float*)((char*)d_ws + 65536);

    spline_setup<<<1, 1024, 0, stream>>>(cps, g_rec, g_meta);

    const int blocks = 512;   // 2 blocks/CU x 256 CUs, 32 waves/CU
    spline_eval<<<blocks, 1024, 0, stream>>>(tq, g_rec, g_meta, out, n);
}